// Round 1
// baseline (303.195 us; speedup 1.0000x reference)
//
#include <hip/hip_runtime.h>

typedef float v4 __attribute__((ext_vector_type(4)));
typedef float f32x4 __attribute__((ext_vector_type(4)));
typedef short bf16x8 __attribute__((ext_vector_type(8)));

#define TWO_PI_256 0.024543692606170259f  // 2*pi/256

// Geometry: B=16, Ci=32, Co=32, H=256, W=256, modes M=16.
// k0: trig table (bf16 split) Th/Tl[o][k] for k1; B-fragment tables Bh/Bl for k4
// K1: w-DFT  x[bc*H + h][256] -> F[row][32]  via split-bf16 MFMA (hi*hi+lo*hi+hi*lo)
// K2: h-DFT  F -> X[bc][ky][kx] complex
// K3: mix    Y[b][co][ky][kx] = sum_ci X[b][ci] * Wc[ci][co]
// K4: inverse. phase1 (VALU): G[h][kx] = sum_ky Y e^{+i ky h th} into LDS.
//     phase2 (MFMA GEMM): out[h][w] = sum_{k=0..31} G[h][k] * B[k][w],
//     B[0]=1/65536, B[kx]=2cos(kx w th)/65536, B[16]=0, B[16+kx]=-2sin(kx w th)/65536.

__device__ __forceinline__ unsigned short f2bf(float f) {
  const unsigned int u = __float_as_uint(f);
  return (unsigned short)((u + 0x7fffu + ((u >> 16) & 1u)) >> 16);  // RNE
}
__device__ __forceinline__ float bf2f(unsigned short h) {
  return __uint_as_float(((unsigned int)h) << 16);
}

__global__ __launch_bounds__(256) void k0_trig(unsigned short* __restrict__ Th,
                                               unsigned short* __restrict__ Tl,
                                               unsigned short* __restrict__ Bh,
                                               unsigned short* __restrict__ Bl) {
  const int k = threadIdx.x;
#pragma unroll
  for (int kx = 0; kx < 16; ++kx) {
    float sv, cv;
    sincosf((float)((kx * k) & 255) * TWO_PI_256, &sv, &cv);
    const float vals[2] = {cv, -sv};
#pragma unroll
    for (int p = 0; p < 2; ++p) {
      const int o = 2 * kx + p;
      const unsigned short hi = f2bf(vals[p]);
      Th[o * 256 + k] = hi;
      Tl[o * 256 + k] = f2bf(vals[p] - bf2f(hi));
    }
  }
  // B-fragment tables for k4 inverse-w GEMM, stored in MFMA B-fragment order:
  // idx = (nt*64 + lane)*8 + j ; lane=(q*16+n16) holds B[k=q*8+j][w=nt*16+n16]
  for (int idx = threadIdx.x; idx < 8192; idx += 256) {
    const int nt = idx >> 9;
    const int lane = (idx >> 3) & 63;
    const int j = idx & 7;
    const int q = lane >> 4;
    const int n16 = lane & 15;
    const int kk = q * 8 + j;
    const int w = nt * 16 + n16;
    float val;
    if (kk == 0) {
      val = 1.f / 65536.f;
    } else if (kk == 16) {
      val = 0.f;  // Im(G[0]) is discarded by irfft
    } else {
      const int kx = kk & 15;
      float sv, cv;
      sincosf((float)((kx * w) & 255) * TWO_PI_256, &sv, &cv);
      val = (kk < 16 ? 2.f * cv : -2.f * sv) * (1.f / 65536.f);
    }
    const unsigned short hi = f2bf(val);
    Bh[idx] = hi;
    Bl[idx] = f2bf(val - bf2f(hi));
  }
}

typedef __attribute__((address_space(1))) const unsigned int gas_u32;
typedef __attribute__((address_space(3))) unsigned int las_u32;

__global__ __launch_bounds__(256) void k1_dftw(const float* __restrict__ x,
                                               const unsigned short* __restrict__ Th,
                                               const unsigned short* __restrict__ Tl,
                                               float* __restrict__ F) {
  __shared__ float Xs[128 * 32];                          // [row][k] fp32, unpadded (glb_load_lds)
  __shared__ __align__(16) unsigned short Ts[2][32 * 264];  // [fmt][o][k] bf16, padded rows
  const int tid = threadIdx.x;
  const int lane = tid & 63;
  const int w = tid >> 6;
  const long rblk = (long)blockIdx.x * 128;
  // stage T once: thread -> (o = tid>>3, k-block = (tid&7)*32)
  {
    const int o = tid >> 3, kb = (tid & 7) * 32;
#pragma unroll
    for (int f = 0; f < 2; ++f) {
      const unsigned short* src = (f ? Tl : Th) + o * 256 + kb;
      unsigned short* dst = &Ts[f][o * 264 + kb];
#pragma unroll
      for (int j = 0; j < 32; j += 8)
        *(bf16x8*)(dst + j) = *(const bf16x8*)(src + j);
    }
  }
  const int q = lane >> 4;    // 0..3
  const int n16 = lane & 15;  // 0..15
  f32x4 acc[2][2] = {};
  for (int kc = 0; kc < 256; kc += 32) {
    __syncthreads();
    // stage Xs: wave w covers rows [w*32, w*32+32), 4 x 1KB lane-linear DMA
#pragma unroll
    for (int i = 0; i < 4; ++i) {
      const int r0 = w * 32 + i * 8;
      __builtin_amdgcn_global_load_lds(
          (gas_u32*)(x + (rblk + r0 + (lane >> 3)) * 256 + kc + (lane & 7) * 4),
          (las_u32*)((unsigned int*)Xs + r0 * 32), 16, 0, 0);
    }
    __syncthreads();
    // B fragments: B[k][n], n = lane&15 -> o, k = q*8+j (contiguous bf16)
    bf16x8 bh[2], bl[2];
#pragma unroll
    for (int nt = 0; nt < 2; ++nt) {
      const int o = nt * 16 + n16;
      bh[nt] = *(const bf16x8*)&Ts[0][o * 264 + kc + q * 8];
      bl[nt] = *(const bf16x8*)&Ts[1][o * 264 + kc + q * 8];
    }
#pragma unroll
    for (int mt = 0; mt < 2; ++mt) {
      // A fragment: A[m][k], m = lane&15, k = q*8+j
      const int m = w * 32 + mt * 16 + n16;
      const float* ap = &Xs[m * 32 + q * 8];
      const v4 a0 = *(const v4*)ap;
      const v4 a1 = *(const v4*)(ap + 4);
      const float af[8] = {a0[0], a0[1], a0[2], a0[3], a1[0], a1[1], a1[2], a1[3]};
      bf16x8 ah, al;
#pragma unroll
      for (int j = 0; j < 8; ++j) {
        const unsigned short h = f2bf(af[j]);
        ah[j] = (short)h;
        al[j] = (short)f2bf(af[j] - bf2f(h));
      }
#pragma unroll
      for (int nt = 0; nt < 2; ++nt) {
        acc[mt][nt] = __builtin_amdgcn_mfma_f32_16x16x32_bf16(ah, bh[nt], acc[mt][nt], 0, 0, 0);
        acc[mt][nt] = __builtin_amdgcn_mfma_f32_16x16x32_bf16(al, bh[nt], acc[mt][nt], 0, 0, 0);
        acc[mt][nt] = __builtin_amdgcn_mfma_f32_16x16x32_bf16(ah, bl[nt], acc[mt][nt], 0, 0, 0);
      }
    }
  }
  // epilogue: row = w*32 + mt*16 + q*4 + reg, col = nt*16 + n16
#pragma unroll
  for (int mt = 0; mt < 2; ++mt)
#pragma unroll
    for (int nt = 0; nt < 2; ++nt)
#pragma unroll
      for (int r = 0; r < 4; ++r) {
        const long row = rblk + w * 32 + mt * 16 + q * 4 + r;
        F[row * 32 + nt * 16 + n16] = acc[mt][nt][r];
      }
}

__global__ __launch_bounds__(256) void k2_dfth(const float* __restrict__ F,
                                               float* __restrict__ X) {
  __shared__ float2 tbl[256];
  __shared__ float Fs[64][36];  // [h][o], stride 36 (16B aligned rows)
  const int tid = threadIdx.x;
  const int bc = blockIdx.x;
  {
    float sv, cv;
    sincosf((float)tid * TWO_PI_256, &sv, &cv);
    tbl[tid] = make_float2(cv, sv);
  }
  const int kx = tid & 15;
  const int ky = tid >> 4;
  float xr = 0.f, xi = 0.f;
  const float* Fb = F + (long)bc * 8192;
  for (int hc = 0; hc < 256; hc += 64) {
    __syncthreads();
#pragma unroll
    for (int p = 0; p < 2; ++p) {
      const int h = (tid >> 3) + p * 32;
      const int j = (tid & 7) * 4;
      *(v4*)&Fs[h][j] = *(const v4*)&Fb[(hc + h) * 32 + j];
    }
    __syncthreads();
#pragma unroll 8
    for (int hl = 0; hl < 64; ++hl) {
      const int h = hc + hl;
      const float2 f = *(const float2*)&Fs[hl][2 * kx];
      const float2 w = tbl[(ky * h) & 255];  // e^{-i th}: (cos, sin)
      xr += f.x * w.x + f.y * w.y;
      xi += f.y * w.x - f.x * w.y;
    }
  }
  *(float2*)&X[((long)bc * 256 + tid) * 2] = make_float2(xr, xi);
}

__global__ __launch_bounds__(256) void k3_mix(const float* __restrict__ X,
                                              const float* __restrict__ Wt,
                                              float* __restrict__ Y) {
  const int t = threadIdx.x;  // mode = ky*16 + kx
  const int co = blockIdx.x;
  const int b = blockIdx.y;
  float yr = 0.f, yi = 0.f;
#pragma unroll 4
  for (int ci = 0; ci < 32; ++ci) {
    const float2 xv = *(const float2*)&X[((long)(b * 32 + ci) * 256 + t) * 2];
    const float2 wv = *(const float2*)&Wt[((long)(ci * 32 + co) * 256 + t) * 2];
    yr += xv.x * wv.x - xv.y * wv.y;
    yi += xv.x * wv.y + xv.y * wv.x;
  }
  *(float2*)&Y[((long)(b * 32 + co) * 256 + t) * 2] = make_float2(yr, yi);
}

// k4: one block = 128 output rows (half of one (b,co) image).
// phase1: h-iDFT Y -> Gs[128][36] (fp32 LDS). A-row layout: [Gr[0..15] | Gi[0..15]]
// phase2: 128x256 = Gs(128x32) x B(32x256) split-bf16 MFMA GEMM, B frags from global (L2).
__global__ __launch_bounds__(256) void k4_inv(const float* __restrict__ Y,
                                              const unsigned short* __restrict__ Bh,
                                              const unsigned short* __restrict__ Bl,
                                              float* __restrict__ out) {
  __shared__ float2 tbl[256];
  __shared__ float2 Ys[256];
  __shared__ float Gs[128][36];  // stride 36: rows 16B-aligned, 2-way banks on A reads
  const int tid = threadIdx.x;
  const int lane = tid & 63;
  const int wv = tid >> 6;
  const int co = blockIdx.x >> 1;
  const int h0 = (blockIdx.x & 1) << 7;
  const int b = blockIdx.y;
  const long bc = b * 32 + co;
  {
    float sv, cv;
    sincosf((float)tid * TWO_PI_256, &sv, &cv);
    tbl[tid] = make_float2(cv, sv);  // (cos, sin) of tid*2pi/256
  }
  Ys[tid] = *(const float2*)&Y[(bc * 256 + tid) * 2];
  __syncthreads();
  {  // phase 1: thread -> (h_local = tid>>1, kx half = tid&1); G = sum_ky Y e^{+i ky h th}
    const int hl = tid >> 1;
    const int p = tid & 1;
    const int h = h0 + hl;
    float gr[8] = {}, gi[8] = {};
#pragma unroll 4
    for (int ky = 0; ky < 16; ++ky) {
      const float2 wt = tbl[(ky * h) & 255];
#pragma unroll
      for (int i = 0; i < 8; ++i) {
        const float2 yv = Ys[ky * 16 + p * 8 + i];
        gr[i] += yv.x * wt.x - yv.y * wt.y;
        gi[i] += yv.x * wt.y + yv.y * wt.x;
      }
    }
#pragma unroll
    for (int i = 0; i < 8; ++i) {
      const int kx = p * 8 + i;
      Gs[hl][kx] = gr[i];       // A cols 0..15  = Gr
      Gs[hl][16 + kx] = gi[i];  // A cols 16..31 = Gi
    }
  }
  __syncthreads();
  // phase 2: MFMA. A frag: m = lane&15 (row within 16-tile), k = q*8+j
  const int q = lane >> 4;
  const int n16 = lane & 15;
  bf16x8 ah[2], al[2];
#pragma unroll
  for (int mt = 0; mt < 2; ++mt) {
    const float* ap = &Gs[wv * 32 + mt * 16 + n16][q * 8];
    const v4 a0 = *(const v4*)ap;
    const v4 a1 = *(const v4*)(ap + 4);
    const float af[8] = {a0[0], a0[1], a0[2], a0[3], a1[0], a1[1], a1[2], a1[3]};
#pragma unroll
    for (int j = 0; j < 8; ++j) {
      const unsigned short hh = f2bf(af[j]);
      ah[mt][j] = (short)hh;
      al[mt][j] = (short)f2bf(af[j] - bf2f(hh));
    }
  }
  f32x4 acc[2][16] = {};
#pragma unroll
  for (int nt = 0; nt < 16; ++nt) {
    const bf16x8 bhf = *(const bf16x8*)&Bh[(nt * 64 + lane) * 8];
    const bf16x8 blf = *(const bf16x8*)&Bl[(nt * 64 + lane) * 8];
#pragma unroll
    for (int mt = 0; mt < 2; ++mt) {
      acc[mt][nt] = __builtin_amdgcn_mfma_f32_16x16x32_bf16(ah[mt], bhf, acc[mt][nt], 0, 0, 0);
      acc[mt][nt] = __builtin_amdgcn_mfma_f32_16x16x32_bf16(al[mt], bhf, acc[mt][nt], 0, 0, 0);
      acc[mt][nt] = __builtin_amdgcn_mfma_f32_16x16x32_bf16(ah[mt], blf, acc[mt][nt], 0, 0, 0);
    }
  }
  // epilogue: row = h0 + wv*32 + mt*16 + q*4 + r, col = nt*16 + n16
  float* __restrict__ ob = out + bc * 65536;
#pragma unroll
  for (int mt = 0; mt < 2; ++mt)
#pragma unroll
    for (int r = 0; r < 4; ++r) {
      const int h = h0 + wv * 32 + mt * 16 + q * 4 + r;
#pragma unroll
      for (int nt = 0; nt < 16; ++nt)
        ob[h * 256 + nt * 16 + n16] = acc[mt][nt][r];
    }
}

extern "C" void kernel_launch(void* const* d_in, const int* in_sizes, int n_in,
                              void* d_out, int out_size, void* d_ws, size_t ws_size,
                              hipStream_t stream) {
  const float* x = (const float*)d_in[0];   // [16][32][256][256]
  const float* wt = (const float*)d_in[1];  // [32][32][16][16][2]
  float* out = (float*)d_out;               // [16][32][256][256]
  float* F = (float*)d_ws;                  // 131072*32 floats = 16.78 MB
  float* X = F + 4194304;                   // 512*256*2 floats = 1 MB
  float* Yv = X + 262144;                   // 512*256*2 floats = 1 MB
  unsigned short* Th = (unsigned short*)(Yv + 262144);  // 32*256 bf16 = 16 KB
  unsigned short* Tl = Th + 8192;                       // 32*256 bf16 = 16 KB
  unsigned short* Bh = Tl + 8192;                       // 16*64*8 bf16 = 16 KB
  unsigned short* Bl = Bh + 8192;                       // 16*64*8 bf16 = 16 KB
  k0_trig<<<1, 256, 0, stream>>>(Th, Tl, Bh, Bl);
  k1_dftw<<<1024, 256, 0, stream>>>(x, Th, Tl, F);
  k2_dfth<<<512, 256, 0, stream>>>(F, X);
  k3_mix<<<dim3(32, 16), 256, 0, stream>>>(X, wt, Yv);
  k4_inv<<<dim3(64, 16), 256, 0, stream>>>(Yv, Bh, Bl, out);
}

// Round 2
// 295.356 us; speedup vs baseline: 1.0265x; 1.0265x over previous
//
#include <hip/hip_runtime.h>

typedef float v4 __attribute__((ext_vector_type(4)));
typedef float f32x4 __attribute__((ext_vector_type(4)));
typedef short bf16x8 __attribute__((ext_vector_type(8)));

#define TWO_PI_256 0.024543692606170259f  // 2*pi/256

// Geometry: B=16, Ci=32, Co=32, H=256, W=256, modes M=16.
// k0 (32 blocks): trig table (bf16 split) Th/Tl[o][k] for k1; B-fragment tables Bh/Bl for kB
// K1: w-DFT  x[bc*H + h][256] -> F[row][32]  via split-bf16 MFMA (hi*hi+lo*hi+hi*lo)
// K2: h-DFT  F -> X[bc][ky][kx] complex. Twiddles via incremental rotation (no LDS table).
// KB: fused mix + inverse.
//   phase0 (VALU): Y[mode] = sum_ci X[b][ci][mode] * Wc[ci][co][mode] into LDS.
//   phase1 (VALU): G[h][kx] = sum_ky Y e^{+i ky h th} into LDS.
//   phase2 (MFMA GEMM): out[h][w] = sum_{k=0..31} G[h][k] * B[k][w],
//     B[0]=1/65536, B[kx]=2cos(kx w th)/65536, B[16]=0, B[16+kx]=-2sin(kx w th)/65536.

__device__ __forceinline__ unsigned short f2bf(float f) {
  const unsigned int u = __float_as_uint(f);
  return (unsigned short)((u + 0x7fffu + ((u >> 16) & 1u)) >> 16);  // RNE
}
__device__ __forceinline__ float bf2f(unsigned short h) {
  return __uint_as_float(((unsigned int)h) << 16);
}

__global__ __launch_bounds__(256) void k0_trig(unsigned short* __restrict__ Th,
                                               unsigned short* __restrict__ Tl,
                                               unsigned short* __restrict__ Bh,
                                               unsigned short* __restrict__ Bl) {
  const int k = threadIdx.x;
  const int o = blockIdx.x;  // 0..31 ; o = 2*kx + p
  {
    const int kx = o >> 1, p = o & 1;
    float sv, cv;
    sincosf((float)((kx * k) & 255) * TWO_PI_256, &sv, &cv);
    const float val = p ? -sv : cv;
    const unsigned short hi = f2bf(val);
    Th[o * 256 + k] = hi;
    Tl[o * 256 + k] = f2bf(val - bf2f(hi));
  }
  // B-fragment tables for kB inverse-w GEMM, stored in MFMA B-fragment order:
  // idx = (nt*64 + lane)*8 + j ; lane=(q*16+n16) holds B[kk=q*8+j][w=nt*16+n16]
  {
    const int idx = o * 256 + k;  // 0..8191
    const int nt = idx >> 9;
    const int lane = (idx >> 3) & 63;
    const int j = idx & 7;
    const int q = lane >> 4;
    const int n16 = lane & 15;
    const int kk = q * 8 + j;
    const int w = nt * 16 + n16;
    float val;
    if (kk == 0) {
      val = 1.f / 65536.f;
    } else if (kk == 16) {
      val = 0.f;  // Im(G[0]) is discarded by irfft
    } else {
      const int kx = kk & 15;
      float sv, cv;
      sincosf((float)((kx * w) & 255) * TWO_PI_256, &sv, &cv);
      val = (kk < 16 ? 2.f * cv : -2.f * sv) * (1.f / 65536.f);
    }
    const unsigned short hi = f2bf(val);
    Bh[idx] = hi;
    Bl[idx] = f2bf(val - bf2f(hi));
  }
}

typedef __attribute__((address_space(1))) const unsigned int gas_u32;
typedef __attribute__((address_space(3))) unsigned int las_u32;

__global__ __launch_bounds__(256) void k1_dftw(const float* __restrict__ x,
                                               const unsigned short* __restrict__ Th,
                                               const unsigned short* __restrict__ Tl,
                                               float* __restrict__ F) {
  __shared__ float Xs[128 * 32];                          // [row][k] fp32, unpadded (glb_load_lds)
  __shared__ __align__(16) unsigned short Ts[2][32 * 264];  // [fmt][o][k] bf16, padded rows
  const int tid = threadIdx.x;
  const int lane = tid & 63;
  const int w = tid >> 6;
  const long rblk = (long)blockIdx.x * 128;
  // stage T once: thread -> (o = tid>>3, k-block = (tid&7)*32)
  {
    const int o = tid >> 3, kb = (tid & 7) * 32;
#pragma unroll
    for (int f = 0; f < 2; ++f) {
      const unsigned short* src = (f ? Tl : Th) + o * 256 + kb;
      unsigned short* dst = &Ts[f][o * 264 + kb];
#pragma unroll
      for (int j = 0; j < 32; j += 8)
        *(bf16x8*)(dst + j) = *(const bf16x8*)(src + j);
    }
  }
  const int q = lane >> 4;    // 0..3
  const int n16 = lane & 15;  // 0..15
  f32x4 acc[2][2] = {};
  for (int kc = 0; kc < 256; kc += 32) {
    __syncthreads();
    // stage Xs: wave w covers rows [w*32, w*32+32), 4 x 1KB lane-linear DMA
#pragma unroll
    for (int i = 0; i < 4; ++i) {
      const int r0 = w * 32 + i * 8;
      __builtin_amdgcn_global_load_lds(
          (gas_u32*)(x + (rblk + r0 + (lane >> 3)) * 256 + kc + (lane & 7) * 4),
          (las_u32*)((unsigned int*)Xs + r0 * 32), 16, 0, 0);
    }
    __syncthreads();
    // B fragments: B[k][n], n = lane&15 -> o, k = q*8+j (contiguous bf16)
    bf16x8 bh[2], bl[2];
#pragma unroll
    for (int nt = 0; nt < 2; ++nt) {
      const int o = nt * 16 + n16;
      bh[nt] = *(const bf16x8*)&Ts[0][o * 264 + kc + q * 8];
      bl[nt] = *(const bf16x8*)&Ts[1][o * 264 + kc + q * 8];
    }
#pragma unroll
    for (int mt = 0; mt < 2; ++mt) {
      // A fragment: A[m][k], m = lane&15, k = q*8+j
      const int m = w * 32 + mt * 16 + n16;
      const float* ap = &Xs[m * 32 + q * 8];
      const v4 a0 = *(const v4*)ap;
      const v4 a1 = *(const v4*)(ap + 4);
      const float af[8] = {a0[0], a0[1], a0[2], a0[3], a1[0], a1[1], a1[2], a1[3]};
      bf16x8 ah, al;
#pragma unroll
      for (int j = 0; j < 8; ++j) {
        const unsigned short h = f2bf(af[j]);
        ah[j] = (short)h;
        al[j] = (short)f2bf(af[j] - bf2f(h));
      }
#pragma unroll
      for (int nt = 0; nt < 2; ++nt) {
        acc[mt][nt] = __builtin_amdgcn_mfma_f32_16x16x32_bf16(ah, bh[nt], acc[mt][nt], 0, 0, 0);
        acc[mt][nt] = __builtin_amdgcn_mfma_f32_16x16x32_bf16(al, bh[nt], acc[mt][nt], 0, 0, 0);
        acc[mt][nt] = __builtin_amdgcn_mfma_f32_16x16x32_bf16(ah, bl[nt], acc[mt][nt], 0, 0, 0);
      }
    }
  }
  // epilogue: row = w*32 + mt*16 + q*4 + reg, col = nt*16 + n16
#pragma unroll
  for (int mt = 0; mt < 2; ++mt)
#pragma unroll
    for (int nt = 0; nt < 2; ++nt)
#pragma unroll
      for (int r = 0; r < 4; ++r) {
        const long row = rblk + w * 32 + mt * 16 + q * 4 + r;
        F[row * 32 + nt * 16 + n16] = acc[mt][nt][r];
      }
}

// k2: h-DFT. Thread = (ky,kx). Twiddle e^{-i ky h th} tracked by incremental
// rotation (1 LDS read per h instead of 2; fp32 drift over 255 steps ~2e-6).
__global__ __launch_bounds__(256) void k2_dfth(const float* __restrict__ F,
                                               float* __restrict__ X) {
  __shared__ float Fs[64][36];  // [h][o], stride 36 (16B aligned rows)
  const int tid = threadIdx.x;
  const int bc = blockIdx.x;
  const int kx = tid & 15;
  const int ky = tid >> 4;
  float sn, cs;
  sincosf((float)ky * TWO_PI_256, &sn, &cs);  // step e^{i ky th} components
  float wr = 1.f, wi = 0.f;                   // w = e^{i ky h th}, h=0
  float xr = 0.f, xi = 0.f;
  const float* Fb = F + (long)bc * 8192;
  for (int hc = 0; hc < 256; hc += 64) {
    __syncthreads();
#pragma unroll
    for (int p = 0; p < 2; ++p) {
      const int h = (tid >> 3) + p * 32;
      const int j = (tid & 7) * 4;
      *(v4*)&Fs[h][j] = *(const v4*)&Fb[(hc + h) * 32 + j];
    }
    __syncthreads();
#pragma unroll 8
    for (int hl = 0; hl < 64; ++hl) {
      const float2 f = *(const float2*)&Fs[hl][2 * kx];
      xr += f.x * wr + f.y * wi;  // X += conj(w) * f
      xi += f.y * wr - f.x * wi;
      const float nwr = wr * cs - wi * sn;
      const float nwi = wr * sn + wi * cs;
      wr = nwr;
      wi = nwi;
    }
  }
  *(float2*)&X[((long)bc * 256 + tid) * 2] = make_float2(xr, xi);
}

// kB: fused mix + inverse. One block = 128 output rows (half of one (b,co) image).
// phase0: Y[t] = sum_ci X[b][ci][t] * Wc[ci][co][t]  (X, Wt L2-resident)
// phase1: h-iDFT Y -> Gs[128][36] (fp32 LDS). A-row layout: [Gr[0..15] | Gi[0..15]]
// phase2: 128x256 = Gs(128x32) x B(32x256) split-bf16 MFMA GEMM, B frags from global (L2).
__global__ __launch_bounds__(256) void kB_mixinv(const float* __restrict__ X,
                                                 const float* __restrict__ Wt,
                                                 const unsigned short* __restrict__ Bh,
                                                 const unsigned short* __restrict__ Bl,
                                                 float* __restrict__ out) {
  __shared__ float2 tbl[256];
  __shared__ float2 Ys[256];
  __shared__ float Gs[128][36];  // stride 36: rows 16B-aligned, 2-way banks on A reads
  const int tid = threadIdx.x;
  const int lane = tid & 63;
  const int wv = tid >> 6;
  const int co = blockIdx.x >> 1;
  const int h0 = (blockIdx.x & 1) << 7;
  const int b = blockIdx.y;
  const long bc = b * 32 + co;
  {
    float sv, cv;
    sincosf((float)tid * TWO_PI_256, &sv, &cv);
    tbl[tid] = make_float2(cv, sv);  // (cos, sin) of tid*2pi/256
  }
  {  // phase 0: mix over ci (redundant across the two h-half blocks; tiny)
    float yr = 0.f, yi = 0.f;
    const float2* Xb = (const float2*)X + (long)b * 8192 + tid;  // + ci*256
    const float2* Wb = (const float2*)Wt + (long)co * 256 + tid;  // + ci*8192
#pragma unroll 8
    for (int ci = 0; ci < 32; ++ci) {
      const float2 xv = Xb[ci * 256];
      const float2 wv2 = Wb[ci * 8192];
      yr += xv.x * wv2.x - xv.y * wv2.y;
      yi += xv.x * wv2.y + xv.y * wv2.x;
    }
    Ys[tid] = make_float2(yr, yi);
  }
  __syncthreads();
  {  // phase 1: thread -> (h_local = tid>>1, kx half = tid&1); G = sum_ky Y e^{+i ky h th}
    const int hl = tid >> 1;
    const int p = tid & 1;
    const int h = h0 + hl;
    float gr[8] = {}, gi[8] = {};
#pragma unroll 4
    for (int ky = 0; ky < 16; ++ky) {
      const float2 wt = tbl[(ky * h) & 255];
#pragma unroll
      for (int i = 0; i < 8; ++i) {
        const float2 yv = Ys[ky * 16 + p * 8 + i];
        gr[i] += yv.x * wt.x - yv.y * wt.y;
        gi[i] += yv.x * wt.y + yv.y * wt.x;
      }
    }
#pragma unroll
    for (int i = 0; i < 8; ++i) {
      const int kx = p * 8 + i;
      Gs[hl][kx] = gr[i];       // A cols 0..15  = Gr
      Gs[hl][16 + kx] = gi[i];  // A cols 16..31 = Gi
    }
  }
  __syncthreads();
  // phase 2: MFMA. A frag: m = lane&15 (row within 16-tile), k = q*8+j
  const int q = lane >> 4;
  const int n16 = lane & 15;
  bf16x8 ah[2], al[2];
#pragma unroll
  for (int mt = 0; mt < 2; ++mt) {
    const float* ap = &Gs[wv * 32 + mt * 16 + n16][q * 8];
    const v4 a0 = *(const v4*)ap;
    const v4 a1 = *(const v4*)(ap + 4);
    const float af[8] = {a0[0], a0[1], a0[2], a0[3], a1[0], a1[1], a1[2], a1[3]};
#pragma unroll
    for (int j = 0; j < 8; ++j) {
      const unsigned short hh = f2bf(af[j]);
      ah[mt][j] = (short)hh;
      al[mt][j] = (short)f2bf(af[j] - bf2f(hh));
    }
  }
  f32x4 acc[2][16] = {};
#pragma unroll
  for (int nt = 0; nt < 16; ++nt) {
    const bf16x8 bhf = *(const bf16x8*)&Bh[(nt * 64 + lane) * 8];
    const bf16x8 blf = *(const bf16x8*)&Bl[(nt * 64 + lane) * 8];
#pragma unroll
    for (int mt = 0; mt < 2; ++mt) {
      acc[mt][nt] = __builtin_amdgcn_mfma_f32_16x16x32_bf16(ah[mt], bhf, acc[mt][nt], 0, 0, 0);
      acc[mt][nt] = __builtin_amdgcn_mfma_f32_16x16x32_bf16(al[mt], bhf, acc[mt][nt], 0, 0, 0);
      acc[mt][nt] = __builtin_amdgcn_mfma_f32_16x16x32_bf16(ah[mt], blf, acc[mt][nt], 0, 0, 0);
    }
  }
  // epilogue: row = h0 + wv*32 + mt*16 + q*4 + r, col = nt*16 + n16
  float* __restrict__ ob = out + bc * 65536;
#pragma unroll
  for (int mt = 0; mt < 2; ++mt)
#pragma unroll
    for (int r = 0; r < 4; ++r) {
      const int h = h0 + wv * 32 + mt * 16 + q * 4 + r;
#pragma unroll
      for (int nt = 0; nt < 16; ++nt)
        ob[h * 256 + nt * 16 + n16] = acc[mt][nt][r];
    }
}

extern "C" void kernel_launch(void* const* d_in, const int* in_sizes, int n_in,
                              void* d_out, int out_size, void* d_ws, size_t ws_size,
                              hipStream_t stream) {
  const float* x = (const float*)d_in[0];   // [16][32][256][256]
  const float* wt = (const float*)d_in[1];  // [32][32][16][16][2]
  float* out = (float*)d_out;               // [16][32][256][256]
  float* F = (float*)d_ws;                  // 131072*32 floats = 16.78 MB
  float* X = F + 4194304;                   // 512*256*2 floats = 1 MB
  unsigned short* Th = (unsigned short*)(X + 262144);  // 32*256 bf16 = 16 KB
  unsigned short* Tl = Th + 8192;                      // 32*256 bf16 = 16 KB
  unsigned short* Bh = Tl + 8192;                      // 16*64*8 bf16 = 16 KB
  unsigned short* Bl = Bh + 8192;                      // 16*64*8 bf16 = 16 KB
  k0_trig<<<32, 256, 0, stream>>>(Th, Tl, Bh, Bl);
  k1_dftw<<<1024, 256, 0, stream>>>(x, Th, Tl, F);
  k2_dfth<<<512, 256, 0, stream>>>(F, X);
  kB_mixinv<<<dim3(64, 16), 256, 0, stream>>>(X, wt, Bh, Bl, out);
}

// Round 3
// 265.861 us; speedup vs baseline: 1.1404x; 1.1109x over previous
//
#include <hip/hip_runtime.h>

typedef float v4 __attribute__((ext_vector_type(4)));
typedef float f32x4 __attribute__((ext_vector_type(4)));
typedef short bf16x8 __attribute__((ext_vector_type(8)));

#define TWO_PI_256 0.024543692606170259f  // 2*pi/256

// Geometry: B=16, Ci=32, Co=32, H=256, W=256, modes M=16.
// k0 (32 blocks): trig tables Th/Tl[o][k] for k12; B-fragment tables Bh/Bl for kB.
// k12: per block = one bc. w-DFT (split-bf16 MFMA, XOR-swizzled staging) -> Fs in LDS,
//      then h-DFT (incremental rotation) -> X[bc][ky][kx] complex. No F global round-trip.
// kB:  per block = one (b,co). mix over ci -> h-iDFT -> inverse-w GEMM (MFMA) -> out.
//      B[0]=1/65536, B[kx]=2cos(kx w th)/65536, B[16]=0, B[16+kx]=-2sin(kx w th)/65536.

__device__ __forceinline__ unsigned short f2bf(float f) {
  const unsigned int u = __float_as_uint(f);
  return (unsigned short)((u + 0x7fffu + ((u >> 16) & 1u)) >> 16);  // RNE
}
__device__ __forceinline__ float bf2f(unsigned short h) {
  return __uint_as_float(((unsigned int)h) << 16);
}

__global__ __launch_bounds__(256) void k0_trig(unsigned short* __restrict__ Th,
                                               unsigned short* __restrict__ Tl,
                                               unsigned short* __restrict__ Bh,
                                               unsigned short* __restrict__ Bl) {
  const int k = threadIdx.x;
  const int o = blockIdx.x;  // 0..31 ; o = 2*kx + p
  {
    const int kx = o >> 1, p = o & 1;
    float sv, cv;
    sincosf((float)((kx * k) & 255) * TWO_PI_256, &sv, &cv);
    const float val = p ? -sv : cv;
    const unsigned short hi = f2bf(val);
    Th[o * 256 + k] = hi;
    Tl[o * 256 + k] = f2bf(val - bf2f(hi));
  }
  // B-fragment tables for kB inverse-w GEMM, MFMA B-fragment order:
  // idx = (nt*64 + lane)*8 + j ; lane=(q*16+n16) holds B[kk=q*8+j][w=nt*16+n16]
  {
    const int idx = o * 256 + k;  // 0..8191
    const int nt = idx >> 9;
    const int lane = (idx >> 3) & 63;
    const int j = idx & 7;
    const int q = lane >> 4;
    const int n16 = lane & 15;
    const int kk = q * 8 + j;
    const int w = nt * 16 + n16;
    float val;
    if (kk == 0) {
      val = 1.f / 65536.f;
    } else if (kk == 16) {
      val = 0.f;  // Im(G[0]) is discarded by irfft
    } else {
      const int kx = kk & 15;
      float sv, cv;
      sincosf((float)((kx * w) & 255) * TWO_PI_256, &sv, &cv);
      val = (kk < 16 ? 2.f * cv : -2.f * sv) * (1.f / 65536.f);
    }
    const unsigned short hi = f2bf(val);
    Bh[idx] = hi;
    Bl[idx] = f2bf(val - bf2f(hi));
  }
}

typedef __attribute__((address_space(1))) const unsigned int gas_u32;
typedef __attribute__((address_space(3))) unsigned int las_u32;

// k12: one block per bc (512 blocks, 256 threads, 4 waves x 64 rows).
// Staging LDS layout is XOR-swizzled: 16B-unit u of row m holds x[m][u ^ (m&7)];
// achieved by pre-swizzling the GLOBAL source col (linear LDS dest for global_load_lds),
// and XOR-ing the b128 read address. A-read start-banks spread 8-way (optimal).
__global__ __launch_bounds__(256) void k12_dft(const float* __restrict__ x,
                                               const unsigned short* __restrict__ Th,
                                               const unsigned short* __restrict__ Tl,
                                               float* __restrict__ X) {
  __shared__ __align__(16) float SXF[256 * 34];  // k-loop: [256][32] swizzled; then Fs [256][34]
  __shared__ __align__(16) unsigned short Ts[2][32 * 264];  // [fmt][o][k] bf16, padded rows
  const int tid = threadIdx.x;
  const int lane = tid & 63;
  const int w = tid >> 6;
  const long bc = blockIdx.x;
  // stage Ts once: thread -> (o = tid>>3, k-block = (tid&7)*32)
  {
    const int o = tid >> 3, kb = (tid & 7) * 32;
#pragma unroll
    for (int f = 0; f < 2; ++f) {
      const unsigned short* src = (f ? Tl : Th) + o * 256 + kb;
      unsigned short* dst = &Ts[f][o * 264 + kb];
#pragma unroll
      for (int j = 0; j < 32; j += 8)
        *(bf16x8*)(dst + j) = *(const bf16x8*)(src + j);
    }
  }
  const int q = lane >> 4;    // 0..3
  const int n16 = lane & 15;  // 0..15
  const int ucol = (lane & 7) ^ (lane >> 3);  // pre-swizzled source 16B-unit
  f32x4 acc[4][2] = {};
  for (int kc = 0; kc < 256; kc += 32) {
    __syncthreads();
    // stage: wave w covers rows [w*64, w*64+64), 8 x 1KB lane-linear DMA, swizzled src col
#pragma unroll
    for (int i = 0; i < 8; ++i) {
      const int r0 = w * 64 + i * 8;
      __builtin_amdgcn_global_load_lds(
          (gas_u32*)(x + (bc * 256 + r0 + (lane >> 3)) * 256 + kc + ucol * 4),
          (las_u32*)((unsigned int*)SXF + r0 * 32), 16, 0, 0);
    }
    __syncthreads();
    // B fragments: B[k][n], n = lane&15 -> o, k = q*8+j (contiguous bf16)
    bf16x8 bh[2], bl[2];
#pragma unroll
    for (int nt = 0; nt < 2; ++nt) {
      const int o = nt * 16 + n16;
      bh[nt] = *(const bf16x8*)&Ts[0][o * 264 + kc + q * 8];
      bl[nt] = *(const bf16x8*)&Ts[1][o * 264 + kc + q * 8];
    }
#pragma unroll
    for (int mt = 0; mt < 4; ++mt) {
      // A fragment: A[m][k], m = lane&15, k = q*8+j ; swizzled read address
      const int m = w * 64 + mt * 16 + n16;
      const int s = n16 & 7;  // == m&7
      const v4 a0 = *(const v4*)&SXF[m * 32 + ((2 * q) ^ s) * 4];
      const v4 a1 = *(const v4*)&SXF[m * 32 + ((2 * q + 1) ^ s) * 4];
      const float af[8] = {a0[0], a0[1], a0[2], a0[3], a1[0], a1[1], a1[2], a1[3]};
      bf16x8 ah, al;
#pragma unroll
      for (int j = 0; j < 8; ++j) {
        const unsigned short h = f2bf(af[j]);
        ah[j] = (short)h;
        al[j] = (short)f2bf(af[j] - bf2f(h));
      }
#pragma unroll
      for (int nt = 0; nt < 2; ++nt) {
        acc[mt][nt] = __builtin_amdgcn_mfma_f32_16x16x32_bf16(ah, bh[nt], acc[mt][nt], 0, 0, 0);
        acc[mt][nt] = __builtin_amdgcn_mfma_f32_16x16x32_bf16(al, bh[nt], acc[mt][nt], 0, 0, 0);
        acc[mt][nt] = __builtin_amdgcn_mfma_f32_16x16x32_bf16(ah, bl[nt], acc[mt][nt], 0, 0, 0);
      }
    }
  }
  __syncthreads();  // Xs (stride-32) dead; safe to overwrite as Fs (stride-34)
  // epilogue to LDS: Fs[row][o], row = w*64 + mt*16 + q*4 + r, o = nt*16 + n16
#pragma unroll
  for (int mt = 0; mt < 4; ++mt)
#pragma unroll
    for (int nt = 0; nt < 2; ++nt)
#pragma unroll
      for (int r = 0; r < 4; ++r)
        SXF[(w * 64 + mt * 16 + q * 4 + r) * 34 + nt * 16 + n16] = acc[mt][nt][r];
  __syncthreads();
  // h-DFT: thread=(ky,kx); X[ky][kx] = sum_h conj(w)^h F[h][kx], incremental rotation
  {
    const int kx = tid & 15;
    const int ky = tid >> 4;
    float sn, cs;
    sincosf((float)ky * TWO_PI_256, &sn, &cs);
    float wr = 1.f, wi = 0.f;
    float xr = 0.f, xi = 0.f;
#pragma unroll 8
    for (int h = 0; h < 256; ++h) {
      const float2 f = *(const float2*)&SXF[h * 34 + 2 * kx];
      xr += f.x * wr + f.y * wi;
      xi += f.y * wr - f.x * wi;
      const float nwr = wr * cs - wi * sn;
      const float nwi = wr * sn + wi * cs;
      wr = nwr;
      wi = nwi;
    }
    *(float2*)&X[(bc * 256 + tid) * 2] = make_float2(xr, xi);
  }
}

// kB: one block per (b,co), 512 threads, 8 waves x 32 rows.
// phase0: Y[t] = sum_ci X[b][ci][t] * Wc[ci][co][t]  (ci split across thread halves)
// phase1: h-iDFT Y -> Gs[256][36]. A-row layout: [Gr[0..15] | Gi[0..15]]
// phase2: 256x256 = Gs(256x32) x B(32x256) split-bf16 MFMA GEMM; per-nt compute+store
//         (no persistent acc array -> low VGPR).
__global__ __launch_bounds__(512) void kB_mixinv(const float* __restrict__ X,
                                                 const float* __restrict__ Wt,
                                                 const unsigned short* __restrict__ Bh,
                                                 const unsigned short* __restrict__ Bl,
                                                 float* __restrict__ out) {
  __shared__ float2 tbl[256];
  __shared__ float2 Yp[2][256];
  __shared__ float Gs[256][36];  // stride 36: A-read start banks spread (optimal)
  const int tid = threadIdx.x;
  const int lane = tid & 63;
  const int wv = tid >> 6;  // 0..7
  const int co = blockIdx.x;
  const int b = blockIdx.y;
  const long bc = b * 32 + co;
  const int t2 = tid & 255;
  const int hf = tid >> 8;  // 0,1
  if (hf == 0) {
    float sv, cv;
    sincosf((float)t2 * TWO_PI_256, &sv, &cv);
    tbl[t2] = make_float2(cv, sv);  // (cos, sin) of t2*2pi/256
  }
  {  // phase 0: mix, ci range split across thread halves
    float yr = 0.f, yi = 0.f;
    const float2* Xp = (const float2*)X + ((long)b * 8192 + t2);   // + ci*256
    const float2* Wp = (const float2*)Wt + ((long)co * 256 + t2);  // + ci*8192
#pragma unroll 8
    for (int ci = hf * 16; ci < hf * 16 + 16; ++ci) {
      const float2 xv = Xp[ci * 256];
      const float2 wv2 = Wp[ci * 8192];
      yr += xv.x * wv2.x - xv.y * wv2.y;
      yi += xv.x * wv2.y + xv.y * wv2.x;
    }
    Yp[hf][t2] = make_float2(yr, yi);
  }
  __syncthreads();
  if (tid < 256) {
    const float2 a = Yp[0][tid], c = Yp[1][tid];
    Yp[0][tid] = make_float2(a.x + c.x, a.y + c.y);
  }
  __syncthreads();
  {  // phase 1: thread -> (h = tid>>1, kx half = tid&1); G = sum_ky Y e^{+i ky h th}
    const int h = tid >> 1;
    const int p = tid & 1;
    float gr[8] = {}, gi[8] = {};
#pragma unroll 4
    for (int ky = 0; ky < 16; ++ky) {
      const float2 wt = tbl[(ky * h) & 255];
#pragma unroll
      for (int i = 0; i < 8; ++i) {
        const float2 yv = Yp[0][ky * 16 + p * 8 + i];
        gr[i] += yv.x * wt.x - yv.y * wt.y;
        gi[i] += yv.x * wt.y + yv.y * wt.x;
      }
    }
#pragma unroll
    for (int i = 0; i < 8; ++i) {
      const int kx = p * 8 + i;
      Gs[h][kx] = gr[i];       // A cols 0..15  = Gr
      Gs[h][16 + kx] = gi[i];  // A cols 16..31 = Gi
    }
  }
  __syncthreads();
  // phase 2: MFMA. A frag: m = lane&15 (row within 16-tile), k = q*8+j
  const int q = lane >> 4;
  const int n16 = lane & 15;
  bf16x8 ah[2], al[2];
#pragma unroll
  for (int mt = 0; mt < 2; ++mt) {
    const float* ap = &Gs[wv * 32 + mt * 16 + n16][q * 8];
    const v4 a0 = *(const v4*)ap;
    const v4 a1 = *(const v4*)(ap + 4);
    const float af[8] = {a0[0], a0[1], a0[2], a0[3], a1[0], a1[1], a1[2], a1[3]};
#pragma unroll
    for (int j = 0; j < 8; ++j) {
      const unsigned short hh = f2bf(af[j]);
      ah[mt][j] = (short)hh;
      al[mt][j] = (short)f2bf(af[j] - bf2f(hh));
    }
  }
  float* __restrict__ ob = out + bc * 65536;
#pragma unroll
  for (int nt = 0; nt < 16; ++nt) {
    const bf16x8 bhf = *(const bf16x8*)&Bh[(nt * 64 + lane) * 8];
    const bf16x8 blf = *(const bf16x8*)&Bl[(nt * 64 + lane) * 8];
    f32x4 c0 = {}, c1 = {};
    c0 = __builtin_amdgcn_mfma_f32_16x16x32_bf16(ah[0], bhf, c0, 0, 0, 0);
    c0 = __builtin_amdgcn_mfma_f32_16x16x32_bf16(al[0], bhf, c0, 0, 0, 0);
    c0 = __builtin_amdgcn_mfma_f32_16x16x32_bf16(ah[0], blf, c0, 0, 0, 0);
    c1 = __builtin_amdgcn_mfma_f32_16x16x32_bf16(ah[1], bhf, c1, 0, 0, 0);
    c1 = __builtin_amdgcn_mfma_f32_16x16x32_bf16(al[1], bhf, c1, 0, 0, 0);
    c1 = __builtin_amdgcn_mfma_f32_16x16x32_bf16(ah[1], blf, c1, 0, 0, 0);
    // rows: h = wv*32 + mt*16 + q*4 + r ; col = nt*16 + n16
#pragma unroll
    for (int r = 0; r < 4; ++r) {
      ob[(wv * 32 + q * 4 + r) * 256 + nt * 16 + n16] = c0[r];
      ob[(wv * 32 + 16 + q * 4 + r) * 256 + nt * 16 + n16] = c1[r];
    }
  }
}

extern "C" void kernel_launch(void* const* d_in, const int* in_sizes, int n_in,
                              void* d_out, int out_size, void* d_ws, size_t ws_size,
                              hipStream_t stream) {
  const float* x = (const float*)d_in[0];   // [16][32][256][256]
  const float* wt = (const float*)d_in[1];  // [32][32][16][16][2]
  float* out = (float*)d_out;               // [16][32][256][256]
  float* X = (float*)d_ws;                  // 512*256*2 floats = 1 MB
  unsigned short* Th = (unsigned short*)(X + 262144);  // 32*256 bf16 = 16 KB
  unsigned short* Tl = Th + 8192;                      // 32*256 bf16 = 16 KB
  unsigned short* Bh = Tl + 8192;                      // 16*64*8 bf16 = 16 KB
  unsigned short* Bl = Bh + 8192;                      // 16*64*8 bf16 = 16 KB
  k0_trig<<<32, 256, 0, stream>>>(Th, Tl, Bh, Bl);
  k12_dft<<<512, 256, 0, stream>>>(x, Th, Tl, X);
  kB_mixinv<<<dim3(32, 16), 512, 0, stream>>>(X, wt, Bh, Bl, out);
}

// Round 4
// 264.509 us; speedup vs baseline: 1.1463x; 1.0051x over previous
//
#include <hip/hip_runtime.h>

typedef float v4 __attribute__((ext_vector_type(4)));
typedef float f32x4 __attribute__((ext_vector_type(4)));
typedef short bf16x8 __attribute__((ext_vector_type(8)));

#define TWO_PI_256 0.024543692606170259f  // 2*pi/256

// Geometry: B=16, Ci=32, Co=32, H=256, W=256, modes M=16.
// k12 (512 blocks x 512 thr): per block = one bc. Inline trig table (hidden under
//      chunk-0 DMA), w-DFT via split-bf16 MFMA (XOR-swizzled staging) -> Fs in LDS,
//      h-DFT (incremental rotation, 256 thr) -> X[bc][ky][kx]. Blocks bc<32 also
//      emit the B-fragment tables Bh/Bl for kB (distributed, 1 entry/thread).
// kB  (512 blocks x 512 thr): per block = one (b,co). mix over ci -> h-iDFT ->
//      inverse-w GEMM (MFMA) -> out.
//      B[0]=1/65536, B[kx]=2cos(kx w th)/65536, B[16]=0, B[16+kx]=-2sin(kx w th)/65536.

__device__ __forceinline__ unsigned short f2bf(float f) {
  const unsigned int u = __float_as_uint(f);
  return (unsigned short)((u + 0x7fffu + ((u >> 16) & 1u)) >> 16);  // RNE
}
__device__ __forceinline__ float bf2f(unsigned short h) {
  return __uint_as_float(((unsigned int)h) << 16);
}

typedef __attribute__((address_space(1))) const unsigned int gas_u32;
typedef __attribute__((address_space(3))) unsigned int las_u32;

// k12: staging LDS is XOR-swizzled: 16B-unit u of row m holds x[m][u ^ (m&7)];
// achieved by pre-swizzling the GLOBAL source col (linear LDS dest for global_load_lds)
// and XOR-ing the b128 read address. A-read start-banks spread 8-way (optimal).
__global__ __launch_bounds__(512) void k12_dft(const float* __restrict__ x,
                                               float* __restrict__ X,
                                               unsigned short* __restrict__ Bh,
                                               unsigned short* __restrict__ Bl) {
  __shared__ __align__(16) float SXF[256 * 34];  // k-loop: [256][32] swizzled; then Fs [256][34]
  __shared__ __align__(16) unsigned short Ts[2][32 * 264];  // [fmt][o][k] bf16, padded rows
  const int tid = threadIdx.x;
  const int lane = tid & 63;
  const int w = tid >> 6;  // 0..7
  const long bc = blockIdx.x;
  const int q = lane >> 4;    // 0..3
  const int n16 = lane & 15;  // 0..15
  const int ucol = (lane & 7) ^ (lane >> 3);  // pre-swizzled source 16B-unit
  f32x4 acc[2][2] = {};
  for (int kc = 0; kc < 256; kc += 32) {
    if (kc) __syncthreads();
    // stage: wave w covers rows [w*32, w*32+32), 4 x 1KB lane-linear DMA, swizzled src col
#pragma unroll
    for (int i = 0; i < 4; ++i) {
      const int r0 = w * 32 + i * 8;
      __builtin_amdgcn_global_load_lds(
          (gas_u32*)(x + (bc * 256 + r0 + (lane >> 3)) * 256 + kc + ucol * 4),
          (las_u32*)((unsigned int*)SXF + r0 * 32), 16, 0, 0);
    }
    if (kc == 0) {
      // Ts inline (VALU, overlaps the in-flight DMA): thread -> (o = tid>>4, 16 k's)
      const int o = tid >> 4;
      const int kxo = o >> 1, p = o & 1;
      const int kb = (tid & 15) * 16;
#pragma unroll 4
      for (int j = 0; j < 16; ++j) {
        const int k = kb + j;
        float sv, cv;
        sincosf((float)((kxo * k) & 255) * TWO_PI_256, &sv, &cv);
        const float val = p ? -sv : cv;
        const unsigned short hi = f2bf(val);
        Ts[0][o * 264 + k] = hi;
        Ts[1][o * 264 + k] = f2bf(val - bf2f(hi));
      }
      // Distributed B-table emit for kB: block bc<32 covers slice idx = bc*256 + tid
      if (bc < 32 && tid < 256) {
        const int idx = (int)bc * 256 + tid;  // 0..8191
        const int nt = idx >> 9;
        const int bl_ = (idx >> 3) & 63;
        const int jj = idx & 7;
        const int kk = (bl_ >> 4) * 8 + jj;
        const int ww = nt * 16 + (bl_ & 15);
        float val;
        if (kk == 0) {
          val = 1.f / 65536.f;
        } else if (kk == 16) {
          val = 0.f;  // Im(G[0]) is discarded by irfft
        } else {
          const int kx = kk & 15;
          float sv, cv;
          sincosf((float)((kx * ww) & 255) * TWO_PI_256, &sv, &cv);
          val = (kk < 16 ? 2.f * cv : -2.f * sv) * (1.f / 65536.f);
        }
        const unsigned short hi = f2bf(val);
        Bh[idx] = hi;
        Bl[idx] = f2bf(val - bf2f(hi));
      }
    }
    __syncthreads();
    // B fragments: B[k][n], n = lane&15 -> o, k = q*8+j (contiguous bf16)
    bf16x8 bh[2], bl[2];
#pragma unroll
    for (int nt = 0; nt < 2; ++nt) {
      const int o = nt * 16 + n16;
      bh[nt] = *(const bf16x8*)&Ts[0][o * 264 + kc + q * 8];
      bl[nt] = *(const bf16x8*)&Ts[1][o * 264 + kc + q * 8];
    }
#pragma unroll
    for (int mt = 0; mt < 2; ++mt) {
      // A fragment: A[m][k], m = lane&15, k = q*8+j ; swizzled read address
      const int m = w * 32 + mt * 16 + n16;
      const int s = n16 & 7;  // == m&7
      const v4 a0 = *(const v4*)&SXF[m * 32 + ((2 * q) ^ s) * 4];
      const v4 a1 = *(const v4*)&SXF[m * 32 + ((2 * q + 1) ^ s) * 4];
      const float af[8] = {a0[0], a0[1], a0[2], a0[3], a1[0], a1[1], a1[2], a1[3]};
      bf16x8 ah, al;
#pragma unroll
      for (int j = 0; j < 8; ++j) {
        const unsigned short h = f2bf(af[j]);
        ah[j] = (short)h;
        al[j] = (short)f2bf(af[j] - bf2f(h));
      }
#pragma unroll
      for (int nt = 0; nt < 2; ++nt) {
        acc[mt][nt] = __builtin_amdgcn_mfma_f32_16x16x32_bf16(ah, bh[nt], acc[mt][nt], 0, 0, 0);
        acc[mt][nt] = __builtin_amdgcn_mfma_f32_16x16x32_bf16(al, bh[nt], acc[mt][nt], 0, 0, 0);
        acc[mt][nt] = __builtin_amdgcn_mfma_f32_16x16x32_bf16(ah, bl[nt], acc[mt][nt], 0, 0, 0);
      }
    }
  }
  __syncthreads();  // staged Xs (stride-32) dead; safe to overwrite as Fs (stride-34)
  // epilogue to LDS: Fs[row][o], row = w*32 + mt*16 + q*4 + r, o = nt*16 + n16
#pragma unroll
  for (int mt = 0; mt < 2; ++mt)
#pragma unroll
    for (int nt = 0; nt < 2; ++nt)
#pragma unroll
      for (int r = 0; r < 4; ++r)
        SXF[(w * 32 + mt * 16 + q * 4 + r) * 34 + nt * 16 + n16] = acc[mt][nt][r];
  __syncthreads();
  // h-DFT (256 threads; order identical to prior rounds -> bit-identical numerics):
  // thread=(ky,kx); X[ky][kx] = sum_h conj(w)^h F[h][kx], incremental rotation
  if (tid < 256) {
    const int kx = tid & 15;
    const int ky = tid >> 4;
    float sn, cs;
    sincosf((float)ky * TWO_PI_256, &sn, &cs);
    float wr = 1.f, wi = 0.f;
    float xr = 0.f, xi = 0.f;
#pragma unroll 8
    for (int h = 0; h < 256; ++h) {
      const float2 f = *(const float2*)&SXF[h * 34 + 2 * kx];
      xr += f.x * wr + f.y * wi;
      xi += f.y * wr - f.x * wi;
      const float nwr = wr * cs - wi * sn;
      const float nwi = wr * sn + wi * cs;
      wr = nwr;
      wi = nwi;
    }
    *(float2*)&X[(bc * 256 + tid) * 2] = make_float2(xr, xi);
  }
}

// kB: one block per (b,co), 512 threads, 8 waves x 32 rows.
// phase0: Y[t] = sum_ci X[b][ci][t] * Wc[ci][co][t]  (ci split across thread halves)
// phase1: h-iDFT Y -> Gs[256][36]. A-row layout: [Gr[0..15] | Gi[0..15]]
// phase2: 256x256 = Gs(256x32) x B(32x256) split-bf16 MFMA GEMM; per-nt compute+store
//         (no persistent acc array -> low VGPR).
__global__ __launch_bounds__(512) void kB_mixinv(const float* __restrict__ X,
                                                 const float* __restrict__ Wt,
                                                 const unsigned short* __restrict__ Bh,
                                                 const unsigned short* __restrict__ Bl,
                                                 float* __restrict__ out) {
  __shared__ float2 tbl[256];
  __shared__ float2 Yp[2][256];
  __shared__ float Gs[256][36];  // stride 36: A-read start banks spread (optimal)
  const int tid = threadIdx.x;
  const int lane = tid & 63;
  const int wv = tid >> 6;  // 0..7
  const int co = blockIdx.x;
  const int b = blockIdx.y;
  const long bc = b * 32 + co;
  const int t2 = tid & 255;
  const int hf = tid >> 8;  // 0,1
  if (hf == 0) {
    float sv, cv;
    sincosf((float)t2 * TWO_PI_256, &sv, &cv);
    tbl[t2] = make_float2(cv, sv);  // (cos, sin) of t2*2pi/256
  }
  {  // phase 0: mix, ci range split across thread halves
    float yr = 0.f, yi = 0.f;
    const float2* Xp = (const float2*)X + ((long)b * 8192 + t2);   // + ci*256
    const float2* Wp = (const float2*)Wt + ((long)co * 256 + t2);  // + ci*8192
#pragma unroll 8
    for (int ci = hf * 16; ci < hf * 16 + 16; ++ci) {
      const float2 xv = Xp[ci * 256];
      const float2 wv2 = Wp[ci * 8192];
      yr += xv.x * wv2.x - xv.y * wv2.y;
      yi += xv.x * wv2.y + xv.y * wv2.x;
    }
    Yp[hf][t2] = make_float2(yr, yi);
  }
  __syncthreads();
  if (tid < 256) {
    const float2 a = Yp[0][tid], c = Yp[1][tid];
    Yp[0][tid] = make_float2(a.x + c.x, a.y + c.y);
  }
  __syncthreads();
  {  // phase 1: thread -> (h = tid>>1, kx half = tid&1); G = sum_ky Y e^{+i ky h th}
    const int h = tid >> 1;
    const int p = tid & 1;
    float gr[8] = {}, gi[8] = {};
#pragma unroll 4
    for (int ky = 0; ky < 16; ++ky) {
      const float2 wt = tbl[(ky * h) & 255];
#pragma unroll
      for (int i = 0; i < 8; ++i) {
        const float2 yv = Yp[0][ky * 16 + p * 8 + i];
        gr[i] += yv.x * wt.x - yv.y * wt.y;
        gi[i] += yv.x * wt.y + yv.y * wt.x;
      }
    }
#pragma unroll
    for (int i = 0; i < 8; ++i) {
      const int kx = p * 8 + i;
      Gs[h][kx] = gr[i];       // A cols 0..15  = Gr
      Gs[h][16 + kx] = gi[i];  // A cols 16..31 = Gi
    }
  }
  __syncthreads();
  // phase 2: MFMA. A frag: m = lane&15 (row within 16-tile), k = q*8+j
  const int q = lane >> 4;
  const int n16 = lane & 15;
  bf16x8 ah[2], al[2];
#pragma unroll
  for (int mt = 0; mt < 2; ++mt) {
    const float* ap = &Gs[wv * 32 + mt * 16 + n16][q * 8];
    const v4 a0 = *(const v4*)ap;
    const v4 a1 = *(const v4*)(ap + 4);
    const float af[8] = {a0[0], a0[1], a0[2], a0[3], a1[0], a1[1], a1[2], a1[3]};
#pragma unroll
    for (int j = 0; j < 8; ++j) {
      const unsigned short hh = f2bf(af[j]);
      ah[mt][j] = (short)hh;
      al[mt][j] = (short)f2bf(af[j] - bf2f(hh));
    }
  }
  float* __restrict__ ob = out + bc * 65536;
#pragma unroll
  for (int nt = 0; nt < 16; ++nt) {
    const bf16x8 bhf = *(const bf16x8*)&Bh[(nt * 64 + lane) * 8];
    const bf16x8 blf = *(const bf16x8*)&Bl[(nt * 64 + lane) * 8];
    f32x4 c0 = {}, c1 = {};
    c0 = __builtin_amdgcn_mfma_f32_16x16x32_bf16(ah[0], bhf, c0, 0, 0, 0);
    c0 = __builtin_amdgcn_mfma_f32_16x16x32_bf16(al[0], bhf, c0, 0, 0, 0);
    c0 = __builtin_amdgcn_mfma_f32_16x16x32_bf16(ah[0], blf, c0, 0, 0, 0);
    c1 = __builtin_amdgcn_mfma_f32_16x16x32_bf16(ah[1], bhf, c1, 0, 0, 0);
    c1 = __builtin_amdgcn_mfma_f32_16x16x32_bf16(al[1], bhf, c1, 0, 0, 0);
    c1 = __builtin_amdgcn_mfma_f32_16x16x32_bf16(ah[1], blf, c1, 0, 0, 0);
    // rows: h = wv*32 + mt*16 + q*4 + r ; col = nt*16 + n16
#pragma unroll
    for (int r = 0; r < 4; ++r) {
      ob[(wv * 32 + q * 4 + r) * 256 + nt * 16 + n16] = c0[r];
      ob[(wv * 32 + 16 + q * 4 + r) * 256 + nt * 16 + n16] = c1[r];
    }
  }
}

extern "C" void kernel_launch(void* const* d_in, const int* in_sizes, int n_in,
                              void* d_out, int out_size, void* d_ws, size_t ws_size,
                              hipStream_t stream) {
  const float* x = (const float*)d_in[0];   // [16][32][256][256]
  const float* wt = (const float*)d_in[1];  // [32][32][16][16][2]
  float* out = (float*)d_out;               // [16][32][256][256]
  float* X = (float*)d_ws;                  // 512*256*2 floats = 1 MB
  unsigned short* Bh = (unsigned short*)(X + 262144);  // 16*64*8 bf16 = 16 KB
  unsigned short* Bl = Bh + 8192;                      // 16*64*8 bf16 = 16 KB
  k12_dft<<<512, 512, 0, stream>>>(x, X, Bh, Bl);
  kB_mixinv<<<dim3(32, 16), 512, 0, stream>>>(X, wt, Bh, Bl, out);
}